// Round 4
// baseline (1027.658 us; speedup 1.0000x reference)
//
#include <hip/hip_runtime.h>
#include <math.h>

// MultiHeadAttention, split-bf16 MFMA pipeline for MI355X (gfx950), round 4.
// Q/K/V stored as PACKED u32 (bf16 hi | lo<<16) - one stream per tensor,
// 256B rows (round-2 memory layout that cached well).  Attention:
// XCD head-pinned block remap, async-stage prefetch (T14), swizzled LDS,
// P hi-only RTN, exp2 softmax.  GEMMs: 3-term split-bf16 MFMA, 128^2 tile.

#define SEQ 2048
#define EMB 1024
#define NB  4
#define NH  16
#define HD  64
#define MR  (NB*SEQ)   // 8192

typedef __attribute__((ext_vector_type(8))) short bf8;   // 8 bf16 (A/B frag)
typedef __attribute__((ext_vector_type(4))) float f4;    // 4 f32  (C/D frag)
typedef unsigned short u16;
typedef unsigned int   u32;

#define MFMA(a,b,c) __builtin_amdgcn_mfma_f32_16x16x32_bf16(a,b,c,0,0,0)
#define QSCALE 0.180336880f   // 0.125 * log2(e)

__device__ __forceinline__ void split1(float x, u16& h, u16& l) {
    u32 u = __float_as_uint(x);
    h = (u16)(u >> 16);                                   // truncated bf16 hi
    float r = x - __uint_as_float(u & 0xffff0000u);       // exact residual
    l = (u16)(__float_as_uint(r) >> 16);                  // bf16 lo
}
__device__ __forceinline__ u16 bf16rtn(float x) {         // round-to-nearest
    u32 u = __float_as_uint(x);
    u += 0x7fff + ((u >> 16) & 1);
    return (u16)(u >> 16);
}
__device__ __forceinline__ u32 packsplit(float v) {
    u16 h, l; split1(v, h, l);
    return (u32)h | ((u32)l << 16);
}
__device__ __forceinline__ void unpk8(const uint4& a, const uint4& b, bf8& h, bf8& l) {
    const u32 uu[8] = {a.x, a.y, a.z, a.w, b.x, b.y, b.z, b.w};
    bf8 hh, ll;
#pragma unroll
    for (int i = 0; i < 8; ++i) {
        hh[i] = (short)(uu[i] & 0xffffu);
        ll[i] = (short)(uu[i] >> 16);
    }
    h = hh; l = ll;
}

// ---------------------------------------------------------------------------
__global__ __launch_bounds__(256)
void split2(const float* __restrict__ src, u16* __restrict__ hi,
            u16* __restrict__ lo, int n4)
{
    int i = blockIdx.x * 256 + threadIdx.x;
    if (i >= n4) return;
    float4 f = ((const float4*)src)[i];
    ushort4 h, l;
    split1(f.x, h.x, l.x); split1(f.y, h.y, l.y);
    split1(f.z, h.z, l.z); split1(f.w, h.w, l.w);
    ((ushort4*)hi)[i] = h;
    ((ushort4*)lo)[i] = l;
}

// ---------------------------------------------------------------------------
// Split-bf16 GEMM, 128x128 tile, BK=32, 4 waves (2x2 of 64x64).
// C[m][n] = sum_k A[m][k]*B[n][k]  (+bias, scale), 3-term split MFMA.
// MODE 1: swapped proj (A=W, B=x); m=feature, n=token.
//         store packed u32 [N,H,S,D] (j along d -> uint4), scaled.
// MODE 2: normal proj  (A=x, B=Wv); m=token, n=feature.
//         store packed u32 V^T [N,H,D,S] (j along s -> uint4).
// MODE 0: swapped final (A=Wo, B=O); m=feature, n=token; fp32 [token][EMB].
// ---------------------------------------------------------------------------
template<int MODE>
__global__ __launch_bounds__(256)
void gemm_split(const u16* __restrict__ Ahi, const u16* __restrict__ Alo,
                const u16* __restrict__ Bhi, const u16* __restrict__ Blo,
                const float* __restrict__ bias, float scale,
                u32* __restrict__ Ypk, float* __restrict__ Yf)
{
    __shared__ __align__(16) u16 As[2][128][40];
    __shared__ __align__(16) u16 Bs[2][128][40];

    const int t  = threadIdx.x;
    const int bm = blockIdx.y * 128, bn = blockIdx.x * 128;
    const int w  = t >> 6, lane = t & 63;
    const int wr = w >> 1, wc = w & 1;
    const int r  = lane & 15, g = lane >> 4;

    f4 acc[4][4];
#pragma unroll
    for (int i = 0; i < 4; ++i)
#pragma unroll
        for (int j = 0; j < 4; ++j)
#pragma unroll
            for (int e = 0; e < 4; ++e) acc[i][j][e] = 0.f;

    for (int k0 = 0; k0 < EMB; k0 += 32) {
        __syncthreads();
#pragma unroll
        for (int p = 0; p < 2; ++p) {
            const int idx = p * 256 + t;
            const int row = idx >> 2, c8 = (idx & 3) * 8;
            *(uint4*)&As[0][row][c8] = *(const uint4*)&Ahi[(size_t)(bm+row)*EMB + k0 + c8];
            *(uint4*)&As[1][row][c8] = *(const uint4*)&Alo[(size_t)(bm+row)*EMB + k0 + c8];
            *(uint4*)&Bs[0][row][c8] = *(const uint4*)&Bhi[(size_t)(bn+row)*EMB + k0 + c8];
            *(uint4*)&Bs[1][row][c8] = *(const uint4*)&Blo[(size_t)(bn+row)*EMB + k0 + c8];
        }
        __syncthreads();

        bf8 ah[4], al[4];
#pragma unroll
        for (int mi = 0; mi < 4; ++mi) {
            ah[mi] = *(const bf8*)&As[0][wr*64 + mi*16 + r][g*8];
            al[mi] = *(const bf8*)&As[1][wr*64 + mi*16 + r][g*8];
        }
#pragma unroll
        for (int ni = 0; ni < 4; ++ni) {
            const bf8 bh = *(const bf8*)&Bs[0][wc*64 + ni*16 + r][g*8];
            const bf8 bl = *(const bf8*)&Bs[1][wc*64 + ni*16 + r][g*8];
#pragma unroll
            for (int mi = 0; mi < 4; ++mi) {
                acc[mi][ni] = MFMA(al[mi], bh, acc[mi][ni]);
                acc[mi][ni] = MFMA(ah[mi], bl, acc[mi][ni]);
                acc[mi][ni] = MFMA(ah[mi], bh, acc[mi][ni]);
            }
        }
    }

#pragma unroll
    for (int mi = 0; mi < 4; ++mi) {
        const int m0 = bm + wr*64 + mi*16 + g*4;   // +j
#pragma unroll
        for (int ni = 0; ni < 4; ++ni) {
            const int n0 = bn + wc*64 + ni*16 + r;
            if (MODE == 1) {
                // m0=feature (j along d), n0=token
                const float4 b4 = *(const float4*)&bias[m0];
                const int h = m0 >> 6, d = m0 & (HD-1);
                const int nn = n0 >> 11, s = n0 & (SEQ-1);
                uint4 pk;
                pk.x = packsplit((acc[mi][ni][0] + b4.x) * scale);
                pk.y = packsplit((acc[mi][ni][1] + b4.y) * scale);
                pk.z = packsplit((acc[mi][ni][2] + b4.z) * scale);
                pk.w = packsplit((acc[mi][ni][3] + b4.w) * scale);
                *(uint4*)&Ypk[(((size_t)nn*NH + h)*SEQ + s)*HD + d] = pk;
            } else if (MODE == 2) {
                // m0=token (j along s), n0=feature
                const float b = bias[n0];
                const int nn = m0 >> 11, s = m0 & (SEQ-1);
                const int h = n0 >> 6, d = n0 & (HD-1);
                uint4 pk;
                pk.x = packsplit(acc[mi][ni][0] + b);
                pk.y = packsplit(acc[mi][ni][1] + b);
                pk.z = packsplit(acc[mi][ni][2] + b);
                pk.w = packsplit(acc[mi][ni][3] + b);
                *(uint4*)&Ypk[(((size_t)nn*NH + h)*HD + d)*SEQ + s] = pk;
            } else {
                const float4 b4 = *(const float4*)&bias[m0];
                float4 o;
                o.x = acc[mi][ni][0] + b4.x; o.y = acc[mi][ni][1] + b4.y;
                o.z = acc[mi][ni][2] + b4.z; o.w = acc[mi][ni][3] + b4.w;
                *(float4*)&Yf[(size_t)n0*EMB + m0] = o;
            }
        }
    }
}

// ---------------------------------------------------------------------------
// Flash attention.  Q/K packed u32 [N,H,S,D]; V packed u32 [N,H,D,S].
// Block = 128 q-rows (4 waves x 32), KV tile 64.  XCD head-pinning:
// all 16 q-blocks of a head share wg%8 -> same XCD L2 holds that head's KV.
// Async-stage prefetch: next tile's global loads issued before PV.
// LDS XOR-swizzle byte ^= (row&7)<<4 on 128B rows; P hi-only RTN per-wave.
// ---------------------------------------------------------------------------
#define LDSRD(arr,row,col) (*(const bf8*)((const char*)(arr) + \
        ((((row)<<7) | ((col)<<1)) ^ (((row)&7)<<4))))

__global__ __launch_bounds__(256, 3)
void attn_mfma(const u32* __restrict__ Qpk, const u32* __restrict__ Kpk,
               const u32* __restrict__ Vpk,
               u16* __restrict__ Ohi, u16* __restrict__ Olo)
{
    __shared__ __align__(16) u16 KH[64*64], KL[64*64];
    __shared__ __align__(16) u16 VH[64*64], VL[64*64];
    __shared__ __align__(16) u16 Ps[4*32*64];

    const int t = threadIdx.x, w = t >> 6, lane = t & 63;
    const int r = lane & 15, g = lane >> 4;
    // head-pinned remap: h%8 == wg%8 (XCD-invariant), qb enumerated within
    const int wg = blockIdx.x;
    const int nh = (wg & 7) | ((wg >> 7) << 3);
    const int qb = (wg >> 3) & 15;
    const int qw = qb * 128 + w * 32;
    const u32* Qb = Qpk + (size_t)nh * SEQ * HD;
    const u32* Kb = Kpk + (size_t)nh * SEQ * HD;
    const u32* Vb = Vpk + (size_t)nh * HD * SEQ;
    u16* Pw = &Ps[w * 32 * 64];

    // ---- Q fragments (pre-scaled+packed in HBM) ----
    bf8 qh[2][2], ql[2][2];
#pragma unroll
    for (int mi = 0; mi < 2; ++mi)
#pragma unroll
        for (int c = 0; c < 2; ++c) {
            const size_t off = (size_t)(qw + mi*16 + r)*HD + c*32 + g*8;
            const uint4 a = *(const uint4*)&Qb[off];
            const uint4 b = *(const uint4*)&Qb[off + 4];
            unpk8(a, b, qh[mi][c], ql[mi][c]);
        }

    f4 oacc[2][4];
    float mrow[2][4], lrow[2][4];
#pragma unroll
    for (int mi = 0; mi < 2; ++mi)
#pragma unroll
        for (int j = 0; j < 4; ++j) {
            mrow[mi][j] = -1e30f; lrow[mi][j] = 0.f;
#pragma unroll
            for (int df = 0; df < 4; ++df) oacc[mi][df][j] = 0.f;
        }

    uint4 kreg[2][2], vreg[2][2];

#define STAGE_LOAD(KT) do { const int kv0_ = (KT) * 64; \
    _Pragma("unroll") for (int p = 0; p < 2; ++p) { \
        const int id_ = p*256 + t, row_ = id_ >> 3, c8_ = (id_ & 7) * 8; \
        const size_t kb_ = (size_t)(kv0_ + row_)*HD + c8_; \
        const size_t vb_ = (size_t)row_*SEQ + kv0_ + c8_; \
        kreg[p][0] = *(const uint4*)&Kb[kb_];     \
        kreg[p][1] = *(const uint4*)&Kb[kb_ + 4]; \
        vreg[p][0] = *(const uint4*)&Vb[vb_];     \
        vreg[p][1] = *(const uint4*)&Vb[vb_ + 4]; \
    } } while (0)

#define STAGE_STORE() do { \
    _Pragma("unroll") for (int p = 0; p < 2; ++p) { \
        const int id_ = p*256 + t, row_ = id_ >> 3, c8_ = (id_ & 7) * 8; \
        const int off_ = ((row_ << 7) | (c8_ << 1)) ^ ((row_ & 7) << 4); \
        bf8 h_, l_; \
        unpk8(kreg[p][0], kreg[p][1], h_, l_); \
        *(bf8*)((char*)KH + off_) = h_; *(bf8*)((char*)KL + off_) = l_; \
        unpk8(vreg[p][0], vreg[p][1], h_, l_); \
        *(bf8*)((char*)VH + off_) = h_; *(bf8*)((char*)VL + off_) = l_; \
    } } while (0)

    STAGE_LOAD(0);

    for (int kt = 0; kt < SEQ/64; ++kt) {
        __syncthreads();            // prior tile's LDS consumers done
        STAGE_STORE();
        __syncthreads();

        // ---- QK^T (3-term split) ----
        f4 s[2][4];
#pragma unroll
        for (int mi = 0; mi < 2; ++mi)
#pragma unroll
            for (int kf = 0; kf < 4; ++kf)
#pragma unroll
                for (int e = 0; e < 4; ++e) s[mi][kf][e] = 0.f;
#pragma unroll
        for (int kf = 0; kf < 4; ++kf) {
#pragma unroll
            for (int c = 0; c < 2; ++c) {
                const int col = c*32 + g*8;
                const bf8 kh = LDSRD(KH, kf*16 + r, col);
                const bf8 kl = LDSRD(KL, kf*16 + r, col);
#pragma unroll
                for (int mi = 0; mi < 2; ++mi) {
                    s[mi][kf] = MFMA(ql[mi][c], kh, s[mi][kf]);
                    s[mi][kf] = MFMA(qh[mi][c], kl, s[mi][kf]);
                    s[mi][kf] = MFMA(qh[mi][c], kh, s[mi][kf]);
                }
            }
        }

        // ---- online softmax (exp2 domain) ----
#pragma unroll
        for (int mi = 0; mi < 2; ++mi)
#pragma unroll
            for (int j = 0; j < 4; ++j) {
                float mx = fmaxf(fmaxf(s[mi][0][j], s[mi][1][j]),
                                 fmaxf(s[mi][2][j], s[mi][3][j]));
                mx = fmaxf(mx, __shfl_xor(mx, 1));
                mx = fmaxf(mx, __shfl_xor(mx, 2));
                mx = fmaxf(mx, __shfl_xor(mx, 4));
                mx = fmaxf(mx, __shfl_xor(mx, 8));
                const float mold = mrow[mi][j];
                const float mnew = fmaxf(mold, mx);
                const float corr = exp2f(mold - mnew);
                mrow[mi][j] = mnew;
                float sum = 0.f;
#pragma unroll
                for (int kf = 0; kf < 4; ++kf) {
                    const float p = exp2f(s[mi][kf][j] - mnew);
                    s[mi][kf][j] = p;
                    sum += p;
                }
                sum += __shfl_xor(sum, 1); sum += __shfl_xor(sum, 2);
                sum += __shfl_xor(sum, 4); sum += __shfl_xor(sum, 8);
                lrow[mi][j] = lrow[mi][j]*corr + sum;
#pragma unroll
                for (int df = 0; df < 4; ++df) oacc[mi][df][j] *= corr;
            }

        // ---- store P (hi-only, RTN) into per-wave swizzled LDS ----
#pragma unroll
        for (int mi = 0; mi < 2; ++mi)
#pragma unroll
            for (int kf = 0; kf < 4; ++kf)
#pragma unroll
                for (int j = 0; j < 4; ++j) {
                    const int row = mi*16 + g*4 + j, col = kf*16 + r;
                    *(u16*)((char*)Pw + (((row<<7) | (col<<1)) ^ ((row&7)<<4)))
                        = bf16rtn(s[mi][kf][j]);
                }

        // ---- async prefetch next K/V tile (lands at next STAGE_STORE) ----
        if (kt + 1 < SEQ/64) STAGE_LOAD(kt + 1);

        // ---- PV: O += P @ V ----
#pragma unroll
        for (int c = 0; c < 2; ++c) {
            const int col = c*32 + g*8;
            bf8 pa[2];
#pragma unroll
            for (int mi = 0; mi < 2; ++mi)
                pa[mi] = LDSRD(Pw, mi*16 + r, col);
#pragma unroll
            for (int df = 0; df < 4; ++df) {
                const bf8 vh = LDSRD(VH, df*16 + r, col);
                const bf8 vl = LDSRD(VL, df*16 + r, col);
#pragma unroll
                for (int mi = 0; mi < 2; ++mi) {
                    oacc[mi][df] = MFMA(pa[mi], vh, oacc[mi][df]);
                    oacc[mi][df] = MFMA(pa[mi], vl, oacc[mi][df]);
                }
            }
        }
    }

    // ---- epilogue: normalize, split, write O hi/lo [token][EMB] ----
    const int n = nh >> 4, h = nh & 15;
#pragma unroll
    for (int mi = 0; mi < 2; ++mi)
#pragma unroll
        for (int j = 0; j < 4; ++j) {
            const float inv = 1.0f / lrow[mi][j];
            const int srow = qw + mi*16 + g*4 + j;
            const size_t base = ((size_t)n*SEQ + srow)*EMB + h*HD;
#pragma unroll
            for (int df = 0; df < 4; ++df) {
                const float v = oacc[mi][df][j] * inv;
                u16 hh, ll; split1(v, hh, ll);
                Ohi[base + df*16 + r] = hh;
                Olo[base + df*16 + r] = ll;
            }
        }
}

// ---------------------------------------------------------------------------
extern "C" void kernel_launch(void* const* d_in, const int* in_sizes, int n_in,
                              void* d_out, int out_size, void* d_ws, size_t ws_size,
                              hipStream_t stream)
{
    const float* x  = (const float*)d_in[0];
    const float* Wq = (const float*)d_in[1];
    const float* bq = (const float*)d_in[2];
    const float* Wk = (const float*)d_in[3];
    const float* bk = (const float*)d_in[4];
    const float* Wv = (const float*)d_in[5];
    const float* bv = (const float*)d_in[6];
    const float* Wo = (const float*)d_in[7];
    const float* bo = (const float*)d_in[8];

    const size_t MB = (size_t)1 << 20;
    char* W = (char*)d_ws;
    u16* xhi = (u16*)(W + 0);            // 16 MB (reused as Ohi)
    u16* xlo = (u16*)(W + 16*MB);        // 16 MB (reused as Olo)
    u16* wsp = (u16*)(W + 32*MB);        // 8 x 2 MB: W splits
    u32* Qpk = (u32*)(W + 48*MB);        // 32 MB packed [N,H,S,D]
    u32* Kpk = (u32*)(W + 80*MB);        // 32 MB packed [N,H,S,D]
    u32* Vpk = (u32*)(W + 112*MB);       // 32 MB packed V^T [N,H,D,S]
    const size_t WN = 1048576;
    u16 *wqh = wsp,        *wql = wsp + WN;
    u16 *wkh = wsp + 2*WN, *wkl = wsp + 3*WN;
    u16 *wvh = wsp + 4*WN, *wvl = wsp + 5*WN;
    u16 *woh = wsp + 6*WN, *wol = wsp + 7*WN;
    u16 *ohi = xhi, *olo = xlo;

    split2<<<dim3(MR*EMB/4/256), dim3(256), 0, stream>>>(x,  xhi, xlo, MR*EMB/4);
    split2<<<dim3(WN/4/256),     dim3(256), 0, stream>>>(Wq, wqh, wql, WN/4);
    split2<<<dim3(WN/4/256),     dim3(256), 0, stream>>>(Wk, wkh, wkl, WN/4);
    split2<<<dim3(WN/4/256),     dim3(256), 0, stream>>>(Wv, wvh, wvl, WN/4);
    split2<<<dim3(WN/4/256),     dim3(256), 0, stream>>>(Wo, woh, wol, WN/4);

    const dim3 blk(256);
    const dim3 gSw(MR/128, EMB/128);   // swapped: (token tiles, feature tiles)
    const dim3 gNm(EMB/128, MR/128);   // normal

    // Q,K: swapped (A=W, B=x) -> packed [N,H,S,D]; Q pre-scaled
    gemm_split<1><<<gSw, blk, 0, stream>>>(wqh, wql, xhi, xlo, bq, QSCALE, Qpk, nullptr);
    gemm_split<1><<<gSw, blk, 0, stream>>>(wkh, wkl, xhi, xlo, bk, 1.0f,   Kpk, nullptr);
    // V: normal (A=x, B=Wv) -> packed V^T [N,H,D,S]
    gemm_split<2><<<gNm, blk, 0, stream>>>(xhi, xlo, wvh, wvl, bv, 1.0f,   Vpk, nullptr);

    attn_mfma<<<dim3(SEQ/128 * NB*NH), blk, 0, stream>>>(Qpk, Kpk, Vpk, ohi, olo);

    // final: swapped (A=Wo, B=O) -> fp32 [token][EMB]
    gemm_split<0><<<gSw, blk, 0, stream>>>(woh, wol, ohi, olo, bo, 1.0f, nullptr, (float*)d_out);
}

// Round 5
// 587.467 us; speedup vs baseline: 1.7493x; 1.7493x over previous
//
#include <hip/hip_runtime.h>
#include <math.h>

// MultiHeadAttention, split-bf16 MFMA pipeline for MI355X (gfx950), round 5.
// Round-2 structure (clean, no spills) + verified deltas only:
//  - packed u32 (bf16 hi | lo<<16) Q/K/V streams, unpacked during staging
//  - XOR-swizzled attn LDS (r3: bank conflicts 2.1e7 -> 0)
//  - P hi-only RTN, exp2-domain softmax, XCD head-pinned block remap
//  - NO __launch_bounds__ occupancy cap, NO held register prefetch
//    (r3/r4 lesson: both caused VGPR spills -> 400MB scratch traffic)

#define SEQ 2048
#define EMB 1024
#define NB  4
#define NH  16
#define HD  64
#define MR  (NB*SEQ)   // 8192

typedef __attribute__((ext_vector_type(8))) short bf8;   // 8 bf16 (A/B frag)
typedef __attribute__((ext_vector_type(4))) float f4;    // 4 f32  (C/D frag)
typedef unsigned short u16;
typedef unsigned int   u32;

#define MFMA(a,b,c) __builtin_amdgcn_mfma_f32_16x16x32_bf16(a,b,c,0,0,0)
#define QSCALE 0.180336880f   // 0.125 * log2(e)

__device__ __forceinline__ void split1(float x, u16& h, u16& l) {
    u32 u = __float_as_uint(x);
    h = (u16)(u >> 16);                                   // truncated bf16 hi
    float r = x - __uint_as_float(u & 0xffff0000u);       // exact residual
    l = (u16)(__float_as_uint(r) >> 16);                  // bf16 lo
}
__device__ __forceinline__ u16 bf16rtn(float x) {         // round-to-nearest
    u32 u = __float_as_uint(x);
    u += 0x7fff + ((u >> 16) & 1);
    return (u16)(u >> 16);
}
__device__ __forceinline__ u32 packsplit(float v) {
    u16 h, l; split1(v, h, l);
    return (u32)h | ((u32)l << 16);
}
__device__ __forceinline__ void unpk8(const uint4& a, const uint4& b, bf8& h, bf8& l) {
    const u32 uu[8] = {a.x, a.y, a.z, a.w, b.x, b.y, b.z, b.w};
    bf8 hh, ll;
#pragma unroll
    for (int i = 0; i < 8; ++i) {
        hh[i] = (short)(uu[i] & 0xffffu);
        ll[i] = (short)(uu[i] >> 16);
    }
    h = hh; l = ll;
}

// ---------------------------------------------------------------------------
__global__ __launch_bounds__(256)
void split2(const float* __restrict__ src, u16* __restrict__ hi,
            u16* __restrict__ lo, int n4)
{
    int i = blockIdx.x * 256 + threadIdx.x;
    if (i >= n4) return;
    float4 f = ((const float4*)src)[i];
    ushort4 h, l;
    split1(f.x, h.x, l.x); split1(f.y, h.y, l.y);
    split1(f.z, h.z, l.z); split1(f.w, h.w, l.w);
    ((ushort4*)hi)[i] = h;
    ((ushort4*)lo)[i] = l;
}

// ---------------------------------------------------------------------------
// Split-bf16 GEMM, 128x128 tile, BK=32, 4 waves (2x2 of 64x64).
// C[m][n] = sum_k A[m][k]*B[n][k]  (+bias, scale), 3-term split MFMA.
// MODE 1: swapped proj (A=W, B=x); m=feature, n=token.
//         store packed u32 [N,H,S,D] (j along d -> uint4), scaled.
// MODE 2: normal proj  (A=x, B=Wv); m=token, n=feature.
//         store packed u32 V^T [N,H,D,S] (j along s -> uint4).
// MODE 0: swapped final (A=Wo, B=O); m=feature, n=token; fp32 [token][EMB].
// ---------------------------------------------------------------------------
template<int MODE>
__global__ __launch_bounds__(256)
void gemm_split(const u16* __restrict__ Ahi, const u16* __restrict__ Alo,
                const u16* __restrict__ Bhi, const u16* __restrict__ Blo,
                const float* __restrict__ bias, float scale,
                u32* __restrict__ Ypk, float* __restrict__ Yf)
{
    __shared__ __align__(16) u16 As[2][128][40];
    __shared__ __align__(16) u16 Bs[2][128][40];

    const int t  = threadIdx.x;
    const int bm = blockIdx.y * 128, bn = blockIdx.x * 128;
    const int w  = t >> 6, lane = t & 63;
    const int wr = w >> 1, wc = w & 1;
    const int r  = lane & 15, g = lane >> 4;

    f4 acc[4][4];
#pragma unroll
    for (int i = 0; i < 4; ++i)
#pragma unroll
        for (int j = 0; j < 4; ++j)
#pragma unroll
            for (int e = 0; e < 4; ++e) acc[i][j][e] = 0.f;

    for (int k0 = 0; k0 < EMB; k0 += 32) {
        __syncthreads();
#pragma unroll
        for (int p = 0; p < 2; ++p) {
            const int idx = p * 256 + t;
            const int row = idx >> 2, c8 = (idx & 3) * 8;
            *(uint4*)&As[0][row][c8] = *(const uint4*)&Ahi[(size_t)(bm+row)*EMB + k0 + c8];
            *(uint4*)&As[1][row][c8] = *(const uint4*)&Alo[(size_t)(bm+row)*EMB + k0 + c8];
            *(uint4*)&Bs[0][row][c8] = *(const uint4*)&Bhi[(size_t)(bn+row)*EMB + k0 + c8];
            *(uint4*)&Bs[1][row][c8] = *(const uint4*)&Blo[(size_t)(bn+row)*EMB + k0 + c8];
        }
        __syncthreads();

        bf8 ah[4], al[4];
#pragma unroll
        for (int mi = 0; mi < 4; ++mi) {
            ah[mi] = *(const bf8*)&As[0][wr*64 + mi*16 + r][g*8];
            al[mi] = *(const bf8*)&As[1][wr*64 + mi*16 + r][g*8];
        }
#pragma unroll
        for (int ni = 0; ni < 4; ++ni) {
            const bf8 bh = *(const bf8*)&Bs[0][wc*64 + ni*16 + r][g*8];
            const bf8 bl = *(const bf8*)&Bs[1][wc*64 + ni*16 + r][g*8];
#pragma unroll
            for (int mi = 0; mi < 4; ++mi) {
                acc[mi][ni] = MFMA(al[mi], bh, acc[mi][ni]);
                acc[mi][ni] = MFMA(ah[mi], bl, acc[mi][ni]);
                acc[mi][ni] = MFMA(ah[mi], bh, acc[mi][ni]);
            }
        }
    }

#pragma unroll
    for (int mi = 0; mi < 4; ++mi) {
        const int m0 = bm + wr*64 + mi*16 + g*4;   // +j
#pragma unroll
        for (int ni = 0; ni < 4; ++ni) {
            const int n0 = bn + wc*64 + ni*16 + r;
            if (MODE == 1) {
                // m0=feature (j along d), n0=token
                const float4 b4 = *(const float4*)&bias[m0];
                const int h = m0 >> 6, d = m0 & (HD-1);
                const int nn = n0 >> 11, s = n0 & (SEQ-1);
                uint4 pk;
                pk.x = packsplit((acc[mi][ni][0] + b4.x) * scale);
                pk.y = packsplit((acc[mi][ni][1] + b4.y) * scale);
                pk.z = packsplit((acc[mi][ni][2] + b4.z) * scale);
                pk.w = packsplit((acc[mi][ni][3] + b4.w) * scale);
                *(uint4*)&Ypk[(((size_t)nn*NH + h)*SEQ + s)*HD + d] = pk;
            } else if (MODE == 2) {
                // m0=token (j along s), n0=feature
                const float b = bias[n0];
                const int nn = m0 >> 11, s = m0 & (SEQ-1);
                const int h = n0 >> 6, d = n0 & (HD-1);
                uint4 pk;
                pk.x = packsplit(acc[mi][ni][0] + b);
                pk.y = packsplit(acc[mi][ni][1] + b);
                pk.z = packsplit(acc[mi][ni][2] + b);
                pk.w = packsplit(acc[mi][ni][3] + b);
                *(uint4*)&Ypk[(((size_t)nn*NH + h)*HD + d)*SEQ + s] = pk;
            } else {
                const float4 b4 = *(const float4*)&bias[m0];
                float4 o;
                o.x = acc[mi][ni][0] + b4.x; o.y = acc[mi][ni][1] + b4.y;
                o.z = acc[mi][ni][2] + b4.z; o.w = acc[mi][ni][3] + b4.w;
                *(float4*)&Yf[(size_t)n0*EMB + m0] = o;
            }
        }
    }
}

// ---------------------------------------------------------------------------
// Flash attention.  Q/K packed u32 [N,H,S,D]; V packed u32 [N,H,D,S].
// Block = 128 q-rows (4 waves x 32), KV tile 64.  XCD head-pinning:
// all 16 q-blocks of a head share wg%8 -> that head's KV stays in one L2.
// LDS XOR-swizzle byte ^= (row&7)<<4 on 128B rows; P hi-only RTN per-wave.
// ---------------------------------------------------------------------------
#define LDSRD(arr,row,col) (*(const bf8*)((const char*)(arr) + \
        ((((row)<<7) | ((col)<<1)) ^ (((row)&7)<<4))))

__global__ __launch_bounds__(256)
void attn_mfma(const u32* __restrict__ Qpk, const u32* __restrict__ Kpk,
               const u32* __restrict__ Vpk,
               u16* __restrict__ Ohi, u16* __restrict__ Olo)
{
    __shared__ __align__(16) u16 KH[64*64], KL[64*64];
    __shared__ __align__(16) u16 VH[64*64], VL[64*64];
    __shared__ __align__(16) u16 Ps[4*32*64];

    const int t = threadIdx.x, w = t >> 6, lane = t & 63;
    const int r = lane & 15, g = lane >> 4;
    // head-pinned remap: h%8 == wg%8 (XCD-invariant), qb enumerated within
    const int wg = blockIdx.x;
    const int nh = (wg & 7) | ((wg >> 7) << 3);
    const int qb = (wg >> 3) & 15;
    const int qw = qb * 128 + w * 32;
    const u32* Qb = Qpk + (size_t)nh * SEQ * HD;
    const u32* Kb = Kpk + (size_t)nh * SEQ * HD;
    const u32* Vb = Vpk + (size_t)nh * HD * SEQ;
    u16* Pw = &Ps[w * 32 * 64];

    // ---- Q fragments (pre-scaled+packed in HBM) ----
    bf8 qh[2][2], ql[2][2];
#pragma unroll
    for (int mi = 0; mi < 2; ++mi)
#pragma unroll
        for (int c = 0; c < 2; ++c) {
            const size_t off = (size_t)(qw + mi*16 + r)*HD + c*32 + g*8;
            const uint4 a = *(const uint4*)&Qb[off];
            const uint4 b = *(const uint4*)&Qb[off + 4];
            unpk8(a, b, qh[mi][c], ql[mi][c]);
        }

    f4 oacc[2][4];
    float mrow[2][4], lrow[2][4];
#pragma unroll
    for (int mi = 0; mi < 2; ++mi)
#pragma unroll
        for (int j = 0; j < 4; ++j) {
            mrow[mi][j] = -1e30f; lrow[mi][j] = 0.f;
#pragma unroll
            for (int df = 0; df < 4; ++df) oacc[mi][df][j] = 0.f;
        }

    for (int kt = 0; kt < SEQ/64; ++kt) {
        const int kv0 = kt * 64;
        __syncthreads();            // prior tile's LDS consumers done
        // ---- stage K,V: load packed, unpack in-register, swizzled store ----
#pragma unroll
        for (int p = 0; p < 2; ++p) {
            const int id = p*256 + t;
            const int row = id >> 3, c8 = (id & 7) * 8;
            const int off = ((row << 7) | (c8 << 1)) ^ ((row & 7) << 4);
            const size_t kb = (size_t)(kv0 + row)*HD + c8;
            const size_t vb = (size_t)row*SEQ + kv0 + c8;
            bf8 h, l;
            {
                const uint4 a = *(const uint4*)&Kb[kb];
                const uint4 b = *(const uint4*)&Kb[kb + 4];
                unpk8(a, b, h, l);
                *(bf8*)((char*)KH + off) = h; *(bf8*)((char*)KL + off) = l;
            }
            {
                const uint4 a = *(const uint4*)&Vb[vb];
                const uint4 b = *(const uint4*)&Vb[vb + 4];
                unpk8(a, b, h, l);
                *(bf8*)((char*)VH + off) = h; *(bf8*)((char*)VL + off) = l;
            }
        }
        __syncthreads();

        // ---- QK^T (3-term split) ----
        f4 s[2][4];
#pragma unroll
        for (int mi = 0; mi < 2; ++mi)
#pragma unroll
            for (int kf = 0; kf < 4; ++kf)
#pragma unroll
                for (int e = 0; e < 4; ++e) s[mi][kf][e] = 0.f;
#pragma unroll
        for (int kf = 0; kf < 4; ++kf) {
#pragma unroll
            for (int c = 0; c < 2; ++c) {
                const int col = c*32 + g*8;
                const bf8 kh = LDSRD(KH, kf*16 + r, col);
                const bf8 kl = LDSRD(KL, kf*16 + r, col);
#pragma unroll
                for (int mi = 0; mi < 2; ++mi) {
                    s[mi][kf] = MFMA(ql[mi][c], kh, s[mi][kf]);
                    s[mi][kf] = MFMA(qh[mi][c], kl, s[mi][kf]);
                    s[mi][kf] = MFMA(qh[mi][c], kh, s[mi][kf]);
                }
            }
        }

        // ---- online softmax (exp2 domain) ----
#pragma unroll
        for (int mi = 0; mi < 2; ++mi)
#pragma unroll
            for (int j = 0; j < 4; ++j) {
                float mx = fmaxf(fmaxf(s[mi][0][j], s[mi][1][j]),
                                 fmaxf(s[mi][2][j], s[mi][3][j]));
                mx = fmaxf(mx, __shfl_xor(mx, 1));
                mx = fmaxf(mx, __shfl_xor(mx, 2));
                mx = fmaxf(mx, __shfl_xor(mx, 4));
                mx = fmaxf(mx, __shfl_xor(mx, 8));
                const float mold = mrow[mi][j];
                const float mnew = fmaxf(mold, mx);
                const float corr = exp2f(mold - mnew);
                mrow[mi][j] = mnew;
                float sum = 0.f;
#pragma unroll
                for (int kf = 0; kf < 4; ++kf) {
                    const float p = exp2f(s[mi][kf][j] - mnew);
                    s[mi][kf][j] = p;
                    sum += p;
                }
                sum += __shfl_xor(sum, 1); sum += __shfl_xor(sum, 2);
                sum += __shfl_xor(sum, 4); sum += __shfl_xor(sum, 8);
                lrow[mi][j] = lrow[mi][j]*corr + sum;
#pragma unroll
                for (int df = 0; df < 4; ++df) oacc[mi][df][j] *= corr;
            }

        // ---- store P (hi-only, RTN) into per-wave swizzled LDS ----
#pragma unroll
        for (int mi = 0; mi < 2; ++mi)
#pragma unroll
            for (int kf = 0; kf < 4; ++kf)
#pragma unroll
                for (int j = 0; j < 4; ++j) {
                    const int row = mi*16 + g*4 + j, col = kf*16 + r;
                    *(u16*)((char*)Pw + (((row<<7) | (col<<1)) ^ ((row&7)<<4)))
                        = bf16rtn(s[mi][kf][j]);
                }

        // ---- PV: O += P @ V ----
#pragma unroll
        for (int c = 0; c < 2; ++c) {
            const int col = c*32 + g*8;
            bf8 pa[2];
#pragma unroll
            for (int mi = 0; mi < 2; ++mi)
                pa[mi] = LDSRD(Pw, mi*16 + r, col);
#pragma unroll
            for (int df = 0; df < 4; ++df) {
                const bf8 vh = LDSRD(VH, df*16 + r, col);
                const bf8 vl = LDSRD(VL, df*16 + r, col);
#pragma unroll
                for (int mi = 0; mi < 2; ++mi) {
                    oacc[mi][df] = MFMA(pa[mi], vh, oacc[mi][df]);
                    oacc[mi][df] = MFMA(pa[mi], vl, oacc[mi][df]);
                }
            }
        }
    }

    // ---- epilogue: normalize, split, write O hi/lo [token][EMB] ----
    const int n = nh >> 4, h = nh & 15;
#pragma unroll
    for (int mi = 0; mi < 2; ++mi)
#pragma unroll
        for (int j = 0; j < 4; ++j) {
            const float inv = 1.0f / lrow[mi][j];
            const int srow = qw + mi*16 + g*4 + j;
            const size_t base = ((size_t)n*SEQ + srow)*EMB + h*HD;
#pragma unroll
            for (int df = 0; df < 4; ++df) {
                const float v = oacc[mi][df][j] * inv;
                u16 hh, ll; split1(v, hh, ll);
                Ohi[base + df*16 + r] = hh;
                Olo[base + df*16 + r] = ll;
            }
        }
}

// ---------------------------------------------------------------------------
extern "C" void kernel_launch(void* const* d_in, const int* in_sizes, int n_in,
                              void* d_out, int out_size, void* d_ws, size_t ws_size,
                              hipStream_t stream)
{
    const float* x  = (const float*)d_in[0];
    const float* Wq = (const float*)d_in[1];
    const float* bq = (const float*)d_in[2];
    const float* Wk = (const float*)d_in[3];
    const float* bk = (const float*)d_in[4];
    const float* Wv = (const float*)d_in[5];
    const float* bv = (const float*)d_in[6];
    const float* Wo = (const float*)d_in[7];
    const float* bo = (const float*)d_in[8];

    const size_t MB = (size_t)1 << 20;
    char* W = (char*)d_ws;
    u16* xhi = (u16*)(W + 0);            // 16 MB (reused as Ohi)
    u16* xlo = (u16*)(W + 16*MB);        // 16 MB (reused as Olo)
    u16* wsp = (u16*)(W + 32*MB);        // 8 x 2 MB: W splits
    u32* Qpk = (u32*)(W + 48*MB);        // 32 MB packed [N,H,S,D]
    u32* Kpk = (u32*)(W + 80*MB);        // 32 MB packed [N,H,S,D]
    u32* Vpk = (u32*)(W + 112*MB);       // 32 MB packed V^T [N,H,D,S]
    const size_t WN = 1048576;
    u16 *wqh = wsp,        *wql = wsp + WN;
    u16 *wkh = wsp + 2*WN, *wkl = wsp + 3*WN;
    u16 *wvh = wsp + 4*WN, *wvl = wsp + 5*WN;
    u16 *woh = wsp + 6*WN, *wol = wsp + 7*WN;
    u16 *ohi = xhi, *olo = xlo;

    split2<<<dim3(MR*EMB/4/256), dim3(256), 0, stream>>>(x,  xhi, xlo, MR*EMB/4);
    split2<<<dim3(WN/4/256),     dim3(256), 0, stream>>>(Wq, wqh, wql, WN/4);
    split2<<<dim3(WN/4/256),     dim3(256), 0, stream>>>(Wk, wkh, wkl, WN/4);
    split2<<<dim3(WN/4/256),     dim3(256), 0, stream>>>(Wv, wvh, wvl, WN/4);
    split2<<<dim3(WN/4/256),     dim3(256), 0, stream>>>(Wo, woh, wol, WN/4);

    const dim3 blk(256);
    const dim3 gSw(MR/128, EMB/128);   // swapped: (token tiles, feature tiles)
    const dim3 gNm(EMB/128, MR/128);   // normal

    // Q,K: swapped (A=W, B=x) -> packed [N,H,S,D]; Q pre-scaled
    gemm_split<1><<<gSw, blk, 0, stream>>>(wqh, wql, xhi, xlo, bq, QSCALE, Qpk, nullptr);
    gemm_split<1><<<gSw, blk, 0, stream>>>(wkh, wkl, xhi, xlo, bk, 1.0f,   Kpk, nullptr);
    // V: normal (A=x, B=Wv) -> packed V^T [N,H,D,S]
    gemm_split<2><<<gNm, blk, 0, stream>>>(xhi, xlo, wvh, wvl, bv, 1.0f,   Vpk, nullptr);

    attn_mfma<<<dim3(SEQ/128 * NB*NH), blk, 0, stream>>>(Qpk, Kpk, Vpk, ohi, olo);

    // final: swapped (A=Wo, B=O) -> fp32 [token][EMB]
    gemm_split<0><<<gSw, blk, 0, stream>>>(woh, wol, ohi, olo, bo, 1.0f, nullptr, (float*)d_out);
}

// Round 6
// 571.200 us; speedup vs baseline: 1.7991x; 1.0285x over previous
//
#include <hip/hip_runtime.h>
#include <math.h>

// MultiHeadAttention, split-bf16 MFMA pipeline for MI355X (gfx950), round 6.
// r5 structure + attn staging made VALU-free:
//  - Q/K/V stored INTERLEAVED hi/lo: [..,S,2,64] (hi 64 u16, then lo 64 u16)
//    -> attention staging is pure uint4 copies (no unpack), Q frags load direct.
//  - attn blocks 512 threads (8 waves x 32 q-rows), 64KB LDS -> 2 blocks/CU.
//  - XOR-swizzled LDS, P hi-only RTN, exp2 softmax, XCD head-pinned remap.
//  - No launch_bounds cap / no held prefetch (r3/r4 spill lessons).

#define SEQ 2048
#define EMB 1024
#define NB  4
#define NH  16
#define HD  64
#define MR  (NB*SEQ)   // 8192

typedef __attribute__((ext_vector_type(8))) short bf8;   // 8 bf16 (A/B frag)
typedef __attribute__((ext_vector_type(4))) float f4;    // 4 f32  (C/D frag)
typedef unsigned short u16;
typedef unsigned int   u32;

#define MFMA(a,b,c) __builtin_amdgcn_mfma_f32_16x16x32_bf16(a,b,c,0,0,0)
#define QSCALE 0.180336880f   // 0.125 * log2(e)

__device__ __forceinline__ void split1(float x, u16& h, u16& l) {
    u32 u = __float_as_uint(x);
    h = (u16)(u >> 16);                                   // truncated bf16 hi
    float r = x - __uint_as_float(u & 0xffff0000u);       // exact residual
    l = (u16)(__float_as_uint(r) >> 16);                  // bf16 lo
}
__device__ __forceinline__ u16 bf16rtn(float x) {         // round-to-nearest
    u32 u = __float_as_uint(x);
    u += 0x7fff + ((u >> 16) & 1);
    return (u16)(u >> 16);
}

// ---------------------------------------------------------------------------
__global__ __launch_bounds__(256)
void split2(const float* __restrict__ src, u16* __restrict__ hi,
            u16* __restrict__ lo, int n4)
{
    int i = blockIdx.x * 256 + threadIdx.x;
    if (i >= n4) return;
    float4 f = ((const float4*)src)[i];
    ushort4 h, l;
    split1(f.x, h.x, l.x); split1(f.y, h.y, l.y);
    split1(f.z, h.z, l.z); split1(f.w, h.w, l.w);
    ((ushort4*)hi)[i] = h;
    ((ushort4*)lo)[i] = l;
}

// ---------------------------------------------------------------------------
// Split-bf16 GEMM, 128x128 tile, BK=32, 4 waves (2x2 of 64x64).
// C[m][n] = sum_k A[m][k]*B[n][k]  (+bias, scale), 3-term split MFMA.
// MODE 1: swapped proj (A=W, B=x); m=feature, n=token.
//         store interleaved u16 [N,H,S,2,HD] (j along d), scaled.
// MODE 2: normal proj  (A=x, B=Wv); m=token, n=feature.
//         store interleaved u16 V^T [N,H,D,2,SEQ] (j along s).
// MODE 0: swapped final (A=Wo, B=O); m=feature, n=token; fp32 [token][EMB].
// ---------------------------------------------------------------------------
template<int MODE>
__global__ __launch_bounds__(256)
void gemm_split(const u16* __restrict__ Ahi, const u16* __restrict__ Alo,
                const u16* __restrict__ Bhi, const u16* __restrict__ Blo,
                const float* __restrict__ bias, float scale,
                u16* __restrict__ Yil, float* __restrict__ Yf)
{
    __shared__ __align__(16) u16 As[2][128][40];
    __shared__ __align__(16) u16 Bs[2][128][40];

    const int t  = threadIdx.x;
    const int bm = blockIdx.y * 128, bn = blockIdx.x * 128;
    const int w  = t >> 6, lane = t & 63;
    const int wr = w >> 1, wc = w & 1;
    const int r  = lane & 15, g = lane >> 4;

    f4 acc[4][4];
#pragma unroll
    for (int i = 0; i < 4; ++i)
#pragma unroll
        for (int j = 0; j < 4; ++j)
#pragma unroll
            for (int e = 0; e < 4; ++e) acc[i][j][e] = 0.f;

    for (int k0 = 0; k0 < EMB; k0 += 32) {
        __syncthreads();
#pragma unroll
        for (int p = 0; p < 2; ++p) {
            const int idx = p * 256 + t;
            const int row = idx >> 2, c8 = (idx & 3) * 8;
            *(uint4*)&As[0][row][c8] = *(const uint4*)&Ahi[(size_t)(bm+row)*EMB + k0 + c8];
            *(uint4*)&As[1][row][c8] = *(const uint4*)&Alo[(size_t)(bm+row)*EMB + k0 + c8];
            *(uint4*)&Bs[0][row][c8] = *(const uint4*)&Bhi[(size_t)(bn+row)*EMB + k0 + c8];
            *(uint4*)&Bs[1][row][c8] = *(const uint4*)&Blo[(size_t)(bn+row)*EMB + k0 + c8];
        }
        __syncthreads();

        bf8 ah[4], al[4];
#pragma unroll
        for (int mi = 0; mi < 4; ++mi) {
            ah[mi] = *(const bf8*)&As[0][wr*64 + mi*16 + r][g*8];
            al[mi] = *(const bf8*)&As[1][wr*64 + mi*16 + r][g*8];
        }
#pragma unroll
        for (int ni = 0; ni < 4; ++ni) {
            const bf8 bh = *(const bf8*)&Bs[0][wc*64 + ni*16 + r][g*8];
            const bf8 bl = *(const bf8*)&Bs[1][wc*64 + ni*16 + r][g*8];
#pragma unroll
            for (int mi = 0; mi < 4; ++mi) {
                acc[mi][ni] = MFMA(al[mi], bh, acc[mi][ni]);
                acc[mi][ni] = MFMA(ah[mi], bl, acc[mi][ni]);
                acc[mi][ni] = MFMA(ah[mi], bh, acc[mi][ni]);
            }
        }
    }

#pragma unroll
    for (int mi = 0; mi < 4; ++mi) {
        const int m0 = bm + wr*64 + mi*16 + g*4;   // +j
#pragma unroll
        for (int ni = 0; ni < 4; ++ni) {
            const int n0 = bn + wc*64 + ni*16 + r;
            if (MODE == 1) {
                // m0=feature (j along d), n0=token
                const float4 b4 = *(const float4*)&bias[m0];
                const int h = m0 >> 6, d = m0 & (HD-1);
                const int nn = n0 >> 11, s = n0 & (SEQ-1);
                ushort4 hh, ll;
                split1((acc[mi][ni][0] + b4.x) * scale, hh.x, ll.x);
                split1((acc[mi][ni][1] + b4.y) * scale, hh.y, ll.y);
                split1((acc[mi][ni][2] + b4.z) * scale, hh.z, ll.z);
                split1((acc[mi][ni][3] + b4.w) * scale, hh.w, ll.w);
                const size_t base = (((size_t)nn*NH + h)*SEQ + s)*(2*HD) + d;
                *(ushort4*)&Yil[base]      = hh;
                *(ushort4*)&Yil[base + HD] = ll;
            } else if (MODE == 2) {
                // m0=token (j along s), n0=feature
                const float b = bias[n0];
                const int nn = m0 >> 11, s = m0 & (SEQ-1);
                const int h = n0 >> 6, d = n0 & (HD-1);
                ushort4 hh, ll;
                split1(acc[mi][ni][0] + b, hh.x, ll.x);
                split1(acc[mi][ni][1] + b, hh.y, ll.y);
                split1(acc[mi][ni][2] + b, hh.z, ll.z);
                split1(acc[mi][ni][3] + b, hh.w, ll.w);
                const size_t base = (((size_t)nn*NH + h)*HD + d)*(2*SEQ) + s;
                *(ushort4*)&Yil[base]       = hh;
                *(ushort4*)&Yil[base + SEQ] = ll;
            } else {
                const float4 b4 = *(const float4*)&bias[m0];
                float4 o;
                o.x = acc[mi][ni][0] + b4.x; o.y = acc[mi][ni][1] + b4.y;
                o.z = acc[mi][ni][2] + b4.z; o.w = acc[mi][ni][3] + b4.w;
                *(float4*)&Yf[(size_t)n0*EMB + m0] = o;
            }
        }
    }
}

// ---------------------------------------------------------------------------
// Flash attention.  Q/K interleaved u16 [N,H,S,2,HD]; V^T [N,H,D,2,SEQ].
// Block = 256 q-rows (8 waves x 32), KV tile 64.  XCD head-pinning:
// all 8 q-blocks of a head share wg%8 -> that head's KV stays in one L2.
// Staging: pure uint4 copies into XOR-swizzled LDS (zero unpack VALU).
// LDS 64KB: K/V hi/lo tiles 32KB + per-wave P (hi-only RTN) 32KB.
// ---------------------------------------------------------------------------
#define LDSRD(arr,row,col) (*(const bf8*)((const char*)(arr) + \
        ((((row)<<7) | ((col)<<1)) ^ (((row)&7)<<4))))

__global__ __launch_bounds__(512)
void attn_mfma(const u16* __restrict__ Qil, const u16* __restrict__ Kil,
               const u16* __restrict__ Vil,
               u16* __restrict__ Ohi, u16* __restrict__ Olo)
{
    __shared__ __align__(16) u16 KH[64*64], KL[64*64];
    __shared__ __align__(16) u16 VH[64*64], VL[64*64];
    __shared__ __align__(16) u16 Ps[8*32*64];

    const int t = threadIdx.x, w = t >> 6, lane = t & 63;
    const int r = lane & 15, g = lane >> 4;
    // head-pinned remap: nh%8 == wg%8 (XCD-invariant), qb enumerated within
    const int wg = blockIdx.x;
    const int nh = (wg & 7) | ((wg >> 6) << 3);
    const int qb = (wg >> 3) & 7;
    const int qw = qb * 256 + w * 32;
    const u16* Qb = Qil + (size_t)nh * SEQ * 2*HD;
    const u16* Kb = Kil + (size_t)nh * SEQ * 2*HD;
    const u16* Vb = Vil + (size_t)nh * HD * 2*SEQ;
    u16* Pw = &Ps[w * 32 * 64];

    // ---- Q fragments: direct bf8 loads (pre-scaled, pre-split in HBM) ----
    bf8 qh[2][2], ql[2][2];
#pragma unroll
    for (int mi = 0; mi < 2; ++mi)
#pragma unroll
        for (int c = 0; c < 2; ++c) {
            const size_t off = (size_t)(qw + mi*16 + r)*(2*HD) + c*32 + g*8;
            qh[mi][c] = *(const bf8*)&Qb[off];
            ql[mi][c] = *(const bf8*)&Qb[off + HD];
        }

    f4 oacc[2][4];
    float mrow[2][4], lrow[2][4];
#pragma unroll
    for (int mi = 0; mi < 2; ++mi)
#pragma unroll
        for (int j = 0; j < 4; ++j) {
            mrow[mi][j] = -1e30f; lrow[mi][j] = 0.f;
#pragma unroll
            for (int df = 0; df < 4; ++df) oacc[mi][df][j] = 0.f;
        }

    for (int kt = 0; kt < SEQ/64; ++kt) {
        const int kv0 = kt * 64;
        __syncthreads();            // prior tile's LDS consumers done
        // ---- stage K,V: pure uint4 copies, swizzled dest, no VALU ----
        {
            const int row = t >> 3, c8 = (t & 7) * 8;
            const int off = ((row << 7) | (c8 << 1)) ^ ((row & 7) << 4);
            const size_t kb = (size_t)(kv0 + row)*(2*HD) + c8;
            const size_t vb = (size_t)row*(2*SEQ) + kv0 + c8;
            *(uint4*)((char*)KH + off) = *(const uint4*)&Kb[kb];
            *(uint4*)((char*)KL + off) = *(const uint4*)&Kb[kb + HD];
            *(uint4*)((char*)VH + off) = *(const uint4*)&Vb[vb];
            *(uint4*)((char*)VL + off) = *(const uint4*)&Vb[vb + SEQ];
        }
        __syncthreads();

        // ---- QK^T (3-term split) ----
        f4 s[2][4];
#pragma unroll
        for (int mi = 0; mi < 2; ++mi)
#pragma unroll
            for (int kf = 0; kf < 4; ++kf)
#pragma unroll
                for (int e = 0; e < 4; ++e) s[mi][kf][e] = 0.f;
#pragma unroll
        for (int kf = 0; kf < 4; ++kf) {
#pragma unroll
            for (int c = 0; c < 2; ++c) {
                const int col = c*32 + g*8;
                const bf8 kh = LDSRD(KH, kf*16 + r, col);
                const bf8 kl = LDSRD(KL, kf*16 + r, col);
#pragma unroll
                for (int mi = 0; mi < 2; ++mi) {
                    s[mi][kf] = MFMA(ql[mi][c], kh, s[mi][kf]);
                    s[mi][kf] = MFMA(qh[mi][c], kl, s[mi][kf]);
                    s[mi][kf] = MFMA(qh[mi][c], kh, s[mi][kf]);
                }
            }
        }

        // ---- online softmax (exp2 domain) ----
#pragma unroll
        for (int mi = 0; mi < 2; ++mi)
#pragma unroll
            for (int j = 0; j < 4; ++j) {
                float mx = fmaxf(fmaxf(s[mi][0][j], s[mi][1][j]),
                                 fmaxf(s[mi][2][j], s[mi][3][j]));
                mx = fmaxf(mx, __shfl_xor(mx, 1));
                mx = fmaxf(mx, __shfl_xor(mx, 2));
                mx = fmaxf(mx, __shfl_xor(mx, 4));
                mx = fmaxf(mx, __shfl_xor(mx, 8));
                const float mold = mrow[mi][j];
                const float mnew = fmaxf(mold, mx);
                const float corr = exp2f(mold - mnew);
                mrow[mi][j] = mnew;
                float sum = 0.f;
#pragma unroll
                for (int kf = 0; kf < 4; ++kf) {
                    const float p = exp2f(s[mi][kf][j] - mnew);
                    s[mi][kf][j] = p;
                    sum += p;
                }
                sum += __shfl_xor(sum, 1); sum += __shfl_xor(sum, 2);
                sum += __shfl_xor(sum, 4); sum += __shfl_xor(sum, 8);
                lrow[mi][j] = lrow[mi][j]*corr + sum;
#pragma unroll
                for (int df = 0; df < 4; ++df) oacc[mi][df][j] *= corr;
            }

        // ---- store P (hi-only, RTN) into per-wave swizzled LDS ----
#pragma unroll
        for (int mi = 0; mi < 2; ++mi)
#pragma unroll
            for (int kf = 0; kf < 4; ++kf)
#pragma unroll
                for (int j = 0; j < 4; ++j) {
                    const int row = mi*16 + g*4 + j, col = kf*16 + r;
                    *(u16*)((char*)Pw + (((row<<7) | (col<<1)) ^ ((row&7)<<4)))
                        = bf16rtn(s[mi][kf][j]);
                }

        // ---- PV: O += P @ V ----
#pragma unroll
        for (int c = 0; c < 2; ++c) {
            const int col = c*32 + g*8;
            bf8 pa[2];
#pragma unroll
            for (int mi = 0; mi < 2; ++mi)
                pa[mi] = LDSRD(Pw, mi*16 + r, col);
#pragma unroll
            for (int df = 0; df < 4; ++df) {
                const bf8 vh = LDSRD(VH, df*16 + r, col);
                const bf8 vl = LDSRD(VL, df*16 + r, col);
#pragma unroll
                for (int mi = 0; mi < 2; ++mi) {
                    oacc[mi][df] = MFMA(pa[mi], vh, oacc[mi][df]);
                    oacc[mi][df] = MFMA(pa[mi], vl, oacc[mi][df]);
                }
            }
        }
    }

    // ---- epilogue: normalize, split, write O hi/lo [token][EMB] ----
    const int n = nh >> 4, h = nh & 15;
#pragma unroll
    for (int mi = 0; mi < 2; ++mi)
#pragma unroll
        for (int j = 0; j < 4; ++j) {
            const float inv = 1.0f / lrow[mi][j];
            const int srow = qw + mi*16 + g*4 + j;
            const size_t base = ((size_t)n*SEQ + srow)*EMB + h*HD;
#pragma unroll
            for (int df = 0; df < 4; ++df) {
                const float v = oacc[mi][df][j] * inv;
                u16 hh, ll; split1(v, hh, ll);
                Ohi[base + df*16 + r] = hh;
                Olo[base + df*16 + r] = ll;
            }
        }
}

// ---------------------------------------------------------------------------
extern "C" void kernel_launch(void* const* d_in, const int* in_sizes, int n_in,
                              void* d_out, int out_size, void* d_ws, size_t ws_size,
                              hipStream_t stream)
{
    const float* x  = (const float*)d_in[0];
    const float* Wq = (const float*)d_in[1];
    const float* bq = (const float*)d_in[2];
    const float* Wk = (const float*)d_in[3];
    const float* bk = (const float*)d_in[4];
    const float* Wv = (const float*)d_in[5];
    const float* bv = (const float*)d_in[6];
    const float* Wo = (const float*)d_in[7];
    const float* bo = (const float*)d_in[8];

    const size_t MB = (size_t)1 << 20;
    char* W = (char*)d_ws;
    u16* xhi = (u16*)(W + 0);            // 16 MB (reused as Ohi)
    u16* xlo = (u16*)(W + 16*MB);        // 16 MB (reused as Olo)
    u16* wsp = (u16*)(W + 32*MB);        // 8 x 2 MB: W splits
    u16* Qil = (u16*)(W + 48*MB);        // 32 MB interleaved [N,H,S,2,HD]
    u16* Kil = (u16*)(W + 80*MB);        // 32 MB interleaved [N,H,S,2,HD]
    u16* Vil = (u16*)(W + 112*MB);       // 32 MB interleaved V^T [N,H,D,2,SEQ]
    const size_t WN = 1048576;
    u16 *wqh = wsp,        *wql = wsp + WN;
    u16 *wkh = wsp + 2*WN, *wkl = wsp + 3*WN;
    u16 *wvh = wsp + 4*WN, *wvl = wsp + 5*WN;
    u16 *woh = wsp + 6*WN, *wol = wsp + 7*WN;
    u16 *ohi = xhi, *olo = xlo;

    split2<<<dim3(MR*EMB/4/256), dim3(256), 0, stream>>>(x,  xhi, xlo, MR*EMB/4);
    split2<<<dim3(WN/4/256),     dim3(256), 0, stream>>>(Wq, wqh, wql, WN/4);
    split2<<<dim3(WN/4/256),     dim3(256), 0, stream>>>(Wk, wkh, wkl, WN/4);
    split2<<<dim3(WN/4/256),     dim3(256), 0, stream>>>(Wv, wvh, wvl, WN/4);
    split2<<<dim3(WN/4/256),     dim3(256), 0, stream>>>(Wo, woh, wol, WN/4);

    const dim3 blk(256);
    const dim3 gSw(MR/128, EMB/128);   // swapped: (token tiles, feature tiles)
    const dim3 gNm(EMB/128, MR/128);   // normal

    // Q,K: swapped (A=W, B=x) -> interleaved [N,H,S,2,HD]; Q pre-scaled
    gemm_split<1><<<gSw, blk, 0, stream>>>(wqh, wql, xhi, xlo, bq, QSCALE, Qil, nullptr);
    gemm_split<1><<<gSw, blk, 0, stream>>>(wkh, wkl, xhi, xlo, bk, 1.0f,   Kil, nullptr);
    // V: normal (A=x, B=Wv) -> interleaved V^T [N,H,D,2,SEQ]
    gemm_split<2><<<gNm, blk, 0, stream>>>(xhi, xlo, wvh, wvl, bv, 1.0f,   Vil, nullptr);

    attn_mfma<<<dim3(SEQ/256 * NB*NH), dim3(512), 0, stream>>>(Qil, Kil, Vil, ohi, olo);

    // final: swapped (A=Wo, B=O) -> fp32 [token][EMB]
    gemm_split<0><<<gSw, blk, 0, stream>>>(woh, wol, ohi, olo, bo, 1.0f, nullptr, (float*)d_out);
}